// Round 21
// baseline (103.449 us; speedup 1.0000x reference)
//
#include <hip/hip_runtime.h>
#include <hip/hip_bf16.h>
#include <math.h>

#define NH   12
#define DM   768
#define DH   64
#define NB   2
#define SEQ  2048

typedef short s8v  __attribute__((ext_vector_type(8)));
typedef short s4v  __attribute__((ext_vector_type(4)));
typedef float f32x4 __attribute__((ext_vector_type(4)));
typedef float f32x16 __attribute__((ext_vector_type(16)));
typedef s8v bfrag;

#define MFMA(a,b,c)   __builtin_amdgcn_mfma_f32_16x16x32_bf16(a,b,c,0,0,0)
#define MFMA32(a,b,c) __builtin_amdgcn_mfma_f32_32x32x16_bf16(a,b,c,0,0,0)

// 0.125 * log2(e)  (1/sqrt(DH) folded with base-2 exp)
#define QSCALE 0.18033688011112042f

__device__ __forceinline__ short f2bf(float f) {
    __hip_bfloat16 h = __float2bfloat16(f);
    return *(short*)&h;
}
__device__ __forceinline__ float bf2f(short s) {
    __hip_bfloat16 h; *(short*)&h = s;
    return __bfloat162float(h);
}
__device__ __forceinline__ float fexp2(float x) { return __builtin_amdgcn_exp2f(x); }
__device__ __forceinline__ unsigned pkbf(float a, float b) {
    unsigned r;
    asm("v_cvt_pk_bf16_f32 %0, %1, %2" : "=v"(r) : "v"(a), "v"(b));
    return r;
}
__device__ __forceinline__ void pl32swap(unsigned &a, unsigned &b) {
    asm volatile("v_permlane32_swap_b32 %0, %1" : "+v"(a), "+v"(b));
}
__device__ __forceinline__ bfrag mkfrag(unsigned d0, unsigned d1, unsigned d2, unsigned d3) {
    union { unsigned u[4]; bfrag f; } X;
    X.u[0] = d0; X.u[1] = d1; X.u[2] = d2; X.u[3] = d3;
    return X.f;
}

// ---------------------------------------------------------------------------
// prep_all: merged prep_x / prep_w / prep_wo (block-range dispatch).
// ---------------------------------------------------------------------------
__global__ __launch_bounds__(256) void prep_all(
    const float* __restrict__ x,
    const float* __restrict__ Wq, const float* __restrict__ Wk,
    const float* __restrict__ Wv, const float* __restrict__ Wo,
    short* __restrict__ xbf, short* __restrict__ Wt,
    short* __restrict__ Wot)
{
    const int bid = blockIdx.x;
    const int t = threadIdx.x;
    __shared__ __align__(16) short T0[64 * 72];

    if (bid < 1536) {
        const size_t gid = (size_t)bid * 256 + t;
        const float4 a = ((const float4*)x)[gid * 2];
        const float4 b = ((const float4*)x)[gid * 2 + 1];
        s8v o;
        o[0]=f2bf(a.x); o[1]=f2bf(a.y); o[2]=f2bf(a.z); o[3]=f2bf(a.w);
        o[4]=f2bf(b.x); o[5]=f2bf(b.y); o[6]=f2bf(b.z); o[7]=f2bf(b.w);
        *(s8v*)&xbf[gid * 8] = o;
    } else if (bid < 1968) {
        const int id = bid - 1536;
        const int dt = id % 12, mh = id / 12;
        const int mat = mh / NH, h = mh % NH;
        const float* W = (mat == 0 ? Wq : mat == 1 ? Wk : Wv) + (size_t)h * DM * DH;
        {
            const int r = t >> 2, e0 = (t & 3) * 16;
            #pragma unroll
            for (int q = 0; q < 4; ++q) {
                const float4 a = *(const float4*)&W[(size_t)(dt * 64 + r) * DH + e0 + q * 4];
                s4v s; s[0]=f2bf(a.x); s[1]=f2bf(a.y); s[2]=f2bf(a.z); s[3]=f2bf(a.w);
                *(s4v*)&T0[r * 72 + e0 + q * 4] = s;
            }
        }
        __syncthreads();
        {
            const int e = t >> 2, r0 = (t & 3) * 16;
            s8v s0, s1;
            #pragma unroll
            for (int i = 0; i < 8; ++i) { s0[i] = T0[(r0 + i) * 72 + e]; s1[i] = T0[(r0 + 8 + i) * 72 + e]; }
            short* dst = Wt + (size_t)mh * DH * DM + (size_t)e * DM + dt * 64 + r0;
            *(s8v*)&dst[0] = s0; *(s8v*)&dst[8] = s1;
        }
    } else {
        const int id = bid - 1968;
        const int ntl = id % 12, ktl = id / 12;
        {
            const int r = t >> 2, n0q = (t & 3) * 16;
            #pragma unroll
            for (int q = 0; q < 4; ++q) {
                const float4 a = *(const float4*)&Wo[(size_t)(ktl * 64 + r) * DM + ntl * 64 + n0q + q * 4];
                s4v s; s[0]=f2bf(a.x); s[1]=f2bf(a.y); s[2]=f2bf(a.z); s[3]=f2bf(a.w);
                *(s4v*)&T0[r * 72 + n0q + q * 4] = s;
            }
        }
        __syncthreads();
        {
            const int n = t >> 2, r0 = (t & 3) * 16;
            s8v h0, h1;
            #pragma unroll
            for (int i = 0; i < 8; ++i) {
                h0[i] = T0[(r0 + i) * 72 + n];
                h1[i] = T0[(r0 + 8 + i) * 72 + n];
            }
            const size_t off = (size_t)(ntl * 64 + n) * DM + ktl * 64 + r0;
            *(s8v*)&Wot[off] = h0; *(s8v*)&Wot[off + 8] = h1;
        }
    }
}

// ---------------------------------------------------------------------------
// qkv_mfma: 128m x 128n tile (TWO heads per block), BK=64, reg-staged.
// grid (32,18). Q written [bh][s][e] pre-scaled by QSCALE.
// K written FRAGMENT-LINEAR:  K_swz[bh][s/32][e/16][(e%16)/8][s%32][e%8]
// V written FRAGMENT-LINEAR:  V_swz[bh][k/32][e/32][(k%32)/16][(k%16)/8][e%32][k%8]
// so attn's per-lane fragment loads are 1KB-contiguous (coalesced).
// ---------------------------------------------------------------------------
__global__ __launch_bounds__(256) void qkv_mfma(
    const short* __restrict__ xbf, const short* __restrict__ Wt,
    const float* __restrict__ bq, const float* __restrict__ bk,
    const float* __restrict__ bv,
    short* __restrict__ qo, short* __restrict__ ko, short* __restrict__ vto)
{
    const int mt = blockIdx.x, sp = blockIdx.y;
    const int slab0 = sp * 2;
    const int mat = slab0 / NH, h0 = slab0 % NH;
    __shared__ __align__(16) short Al[128 * 72];
    __shared__ __align__(16) short Bl[128 * 72];
    const int t = threadIdx.x;
    const int w = t >> 6, lane = t & 63, l15 = lane & 15, g = lane >> 4;
    const int m0 = mt * 128;
    const short* Ws = Wt + (size_t)slab0 * DH * DM;   // 2 slabs contiguous

    f32x4 acc[2][8];
    #pragma unroll
    for (int i = 0; i < 2; ++i)
        #pragma unroll
        for (int j = 0; j < 8; ++j) acc[i][j] = 0.f;

    for (int kt = 0; kt < DM / 64; ++kt) {
        const int k0 = kt * 64;
        {
            const int row = t >> 1, kc = (t & 1) * 32;
            #pragma unroll
            for (int q = 0; q < 4; ++q)
                *(s8v*)&Al[row * 72 + kc + q * 8] = *(const s8v*)&xbf[(size_t)(m0 + row) * DM + k0 + kc + q * 8];
            #pragma unroll
            for (int q = 0; q < 4; ++q)
                *(s8v*)&Bl[row * 72 + kc + q * 8] = *(const s8v*)&Ws[(size_t)row * DM + k0 + kc + q * 8];
        }
        __syncthreads();
        #pragma unroll
        for (int kk = 0; kk < 2; ++kk) {
            bfrag a[2], b[8];
            #pragma unroll
            for (int i = 0; i < 2; ++i) a[i] = *(const bfrag*)&Al[(w * 32 + 16 * i + l15) * 72 + kk * 32 + 8 * g];
            #pragma unroll
            for (int j = 0; j < 8; ++j) b[j] = *(const bfrag*)&Bl[(16 * j + l15) * 72 + kk * 32 + 8 * g];
            #pragma unroll
            for (int i = 0; i < 2; ++i)
                #pragma unroll
                for (int j = 0; j < 8; ++j) acc[i][j] = MFMA(a[i], b[j], acc[i][j]);
        }
        __syncthreads();
    }

    const float* bias0 = (mat == 0 ? bq : mat == 1 ? bk : bv);
    if (mat == 0) {
        #pragma unroll
        for (int j = 0; j < 8; ++j) {
            const int h = h0 + (j >> 2);
            const int n = (j & 3) * 16 + l15;
            const float bia = bias0[h * DH + n];
            #pragma unroll
            for (int i = 0; i < 2; ++i)
                #pragma unroll
                for (int r = 0; r < 4; ++r) {
                    const int m = m0 + w * 32 + 16 * i + 4 * g + r;
                    const int bb = m >> 11, s = m & (SEQ - 1);
                    qo[(((size_t)bb * NH + h) * SEQ + s) * DH + n] = f2bf((acc[i][j][r] + bia) * QSCALE);
                }
        }
    } else if (mat == 1) {
        // K fragment-linear: idx = (s>>5)*2048 + (j&3)*512 + (l15>>3)*256 + (s&31)*8 + (l15&7)
        #pragma unroll
        for (int j = 0; j < 8; ++j) {
            const int h = h0 + (j >> 2);
            const int n = (j & 3) * 16 + l15;
            const float bia = bias0[h * DH + n];
            #pragma unroll
            for (int i = 0; i < 2; ++i)
                #pragma unroll
                for (int r = 0; r < 4; ++r) {
                    const int m = m0 + w * 32 + 16 * i + 4 * g + r;
                    const int bb = m >> 11, s = m & (SEQ - 1);
                    ko[((size_t)bb * NH + h) * (SEQ * DH) + (size_t)(s >> 5) * 2048
                       + (j & 3) * 512 + (l15 >> 3) * 256 + (s & 31) * 8 + (l15 & 7)]
                        = f2bf(acc[i][j][r] + bia);
                }
        }
    } else {
        // V fragment-linear: idx = (k>>5)*2048 + ((j&3)>>1)*1024 + i*512
        //                        + (g>>1)*256 + ((j&1)*16 + l15)*8 + (g&1)*4
        #pragma unroll
        for (int j = 0; j < 8; ++j) {
            const int h = h0 + (j >> 2);
            const int n = (j & 3) * 16 + l15;
            const float bia = bias0[h * DH + n];
            #pragma unroll
            for (int i = 0; i < 2; ++i) {
                const int m = m0 + w * 32 + 16 * i + 4 * g;
                const int bb = m >> 11, k = m & (SEQ - 1);
                s4v sv;
                #pragma unroll
                for (int r = 0; r < 4; ++r) sv[r] = f2bf(acc[i][j][r] + bia);
                *(s4v*)&vto[((size_t)bb * NH + h) * (SEQ * DH) + (size_t)(k >> 5) * 2048
                            + ((j & 3) >> 1) * 1024 + i * 512
                            + (g >> 1) * 256 + ((j & 1) * 16 + l15) * 8 + (g & 1) * 4] = sv;
            }
        }
    }
}

// ---------------------------------------------------------------------------
// attn_mfma: r11 main loop + setprio; K/V in fragment-linear layouts so
// every kf/vf load is a fully-coalesced contiguous 1KB wave load (8 cache
// lines vs 32 strided). Flat grid 768, XCD-swizzled. 4 waves; each wave:
// 64 q-rows x one KV quarter. 48KB combine; ctx written as bf16 [B,S,D].
// ---------------------------------------------------------------------------
__global__ __launch_bounds__(256, 4) void attn_mfma(
    const short* __restrict__ qg, const short* __restrict__ kg,
    const short* __restrict__ vtg, short* __restrict__ ctx)
{
    // n = 8*(qb*3 + bh%3) + bh/3  <=>  xcd=n&7, s=n>>3, bh=xcd*3+s%3, qb=s/3
    const int n_  = blockIdx.x;
    const int xcd = n_ & 7, s_ = n_ >> 3;
    const int bh = xcd * 3 + (s_ % 3);
    const int qb = s_ / 3;
    const int b = bh / NH, h = bh % NH;

    __shared__ __align__(16) float Cb[4][3][16][64];  // 48KB: combine buffer
    __shared__ float Ls[4][2][64];                     // 2KB: l partials

    const int t = threadIdx.x;
    const int w = t >> 6, l = t & 63, lo = l & 31, hi = l >> 5;
    const size_t base  = (size_t)bh * SEQ * DH;
    const int qbase = qb * 64;

    // Q fragments (B operand), Q pre-scaled by QSCALE
    bfrag qf[2][4];
    #pragma unroll
    for (int qt = 0; qt < 2; ++qt)
        #pragma unroll
        for (int esl = 0; esl < 4; ++esl)
            qf[qt][esl] = *(const bfrag*)&qg[base + (size_t)(qbase + qt * 32 + lo) * DH + esl * 16 + hi * 8];

    f32x16 o00, o01, o10, o11;   // o[q-tile][e-tile]
    o00 = 0.f; o01 = 0.f; o10 = 0.f; o11 = 0.f;
    float ls0 = 0.f, ls1 = 0.f;

    const short* kbp = kg + base;    // fragment-linear K
    const short* vbp = vtg + base;   // fragment-linear V
    const int kb0 = w * 16;          // this wave's first 32-row KV chunk

    // softmax + PV step (captures accumulators by reference)
    auto SMPV = [&](const f32x16& s0, const f32x16& s1,
                    const bfrag& vf00, const bfrag& vf01,
                    const bfrag& vf10, const bfrag& vf11) {
        float p0[16], p1[16];
        #pragma unroll
        for (int i = 0; i < 16; ++i) p0[i] = fexp2(s0[i]);
        #pragma unroll
        for (int i = 0; i < 16; ++i) p1[i] = fexp2(s1[i]);
        ls0 += ((p0[0]+p0[1])+(p0[2]+p0[3])) + ((p0[4]+p0[5])+(p0[6]+p0[7]))
             + ((p0[8]+p0[9])+(p0[10]+p0[11])) + ((p0[12]+p0[13])+(p0[14]+p0[15]));
        ls1 += ((p1[0]+p1[1])+(p1[2]+p1[3])) + ((p1[4]+p1[5])+(p1[6]+p1[7]))
             + ((p1[8]+p1[9])+(p1[10]+p1[11])) + ((p1[12]+p1[13])+(p1[14]+p1[15]));

        unsigned a0 = pkbf(p0[0],  p0[1]),  a1 = pkbf(p0[2],  p0[3]);
        unsigned a2 = pkbf(p0[4],  p0[5]),  a3 = pkbf(p0[6],  p0[7]);
        unsigned c0_ = pkbf(p0[8], p0[9]),  c1_ = pkbf(p0[10], p0[11]);
        unsigned c2_ = pkbf(p0[12], p0[13]), c3_ = pkbf(p0[14], p0[15]);
        pl32swap(a0, a2); pl32swap(a1, a3); pl32swap(c0_, c2_); pl32swap(c1_, c3_);
        const bfrag pa00 = mkfrag(a0, a1, a2, a3);
        const bfrag pa01 = mkfrag(c0_, c1_, c2_, c3_);

        unsigned d0 = pkbf(p1[0],  p1[1]),  d1 = pkbf(p1[2],  p1[3]);
        unsigned d2 = pkbf(p1[4],  p1[5]),  d3 = pkbf(p1[6],  p1[7]);
        unsigned e0_ = pkbf(p1[8], p1[9]),  e1_ = pkbf(p1[10], p1[11]);
        unsigned e2_ = pkbf(p1[12], p1[13]), e3_ = pkbf(p1[14], p1[15]);
        pl32swap(d0, d2); pl32swap(d1, d3); pl32swap(e0_, e2_); pl32swap(e1_, e3_);
        const bfrag pa10 = mkfrag(d0, d1, d2, d3);
        const bfrag pa11 = mkfrag(e0_, e1_, e2_, e3_);

        __builtin_amdgcn_s_setprio(1);
        o00 = MFMA32(vf00, pa00, o00); o00 = MFMA32(vf01, pa01, o00);
        o10 = MFMA32(vf00, pa10, o10); o10 = MFMA32(vf01, pa11, o10);
        o01 = MFMA32(vf10, pa00, o01); o01 = MFMA32(vf11, pa01, o01);
        o11 = MFMA32(vf10, pa10, o11); o11 = MFMA32(vf11, pa11, o11);
        __builtin_amdgcn_s_setprio(0);
    };

    bfrag kfA[4], kfB[4];
    bfrag vfA[4], vfB[4];
    // prologue: K and V for iteration 0 (contiguous 1KB loads)
    #pragma unroll
    for (int esl = 0; esl < 4; ++esl)
        kfA[esl] = *(const bfrag*)&kbp[(size_t)kb0 * 2048 + esl * 512 + l * 8];
    #pragma unroll
    for (int q = 0; q < 4; ++q)
        vfA[q] = *(const bfrag*)&vbp[(size_t)kb0 * 2048 + q * 512 + l * 8];

    for (int it2 = 0; it2 < 8; ++it2) {
        // ---- even iteration: current in A, prefetch into B ----
        {
            const int it = 2 * it2;
            f32x16 s0, s1; s0 = 0.f; s1 = 0.f;
            __builtin_amdgcn_s_setprio(1);
            #pragma unroll
            for (int esl = 0; esl < 4; ++esl) {
                s0 = MFMA32(kfA[esl], qf[0][esl], s0);
                s1 = MFMA32(kfA[esl], qf[1][esl], s1);
            }
            __builtin_amdgcn_s_setprio(0);
            // prefetch K,V for iter+1 (covered by softmax+PV below)
            {
                const size_t co = (size_t)(kb0 + it + 1) * 2048;
                #pragma unroll
                for (int esl = 0; esl < 4; ++esl)
                    kfB[esl] = *(const bfrag*)&kbp[co + esl * 512 + l * 8];
                #pragma unroll
                for (int q = 0; q < 4; ++q)
                    vfB[q] = *(const bfrag*)&vbp[co + q * 512 + l * 8];
            }
            SMPV(s0, s1, vfA[0], vfA[1], vfA[2], vfA[3]);
        }
        // ---- odd iteration: current in B, prefetch into A ----
        {
            const int it = 2 * it2 + 1;
            f32x16 s0, s1; s0 = 0.f; s1 = 0.f;
            __builtin_amdgcn_s_setprio(1);
            #pragma unroll
            for (int esl = 0; esl < 4; ++esl) {
                s0 = MFMA32(kfB[esl], qf[0][esl], s0);
                s1 = MFMA32(kfB[esl], qf[1][esl], s1);
            }
            __builtin_amdgcn_s_setprio(0);
            if (it2 < 7) {
                const size_t co = (size_t)(kb0 + it + 1) * 2048;
                #pragma unroll
                for (int esl = 0; esl < 4; ++esl)
                    kfA[esl] = *(const bfrag*)&kbp[co + esl * 512 + l * 8];
                #pragma unroll
                for (int q = 0; q < 4; ++q)
                    vfA[q] = *(const bfrag*)&vbp[co + q * 512 + l * 8];
            }
            SMPV(s0, s1, vfB[0], vfB[1], vfB[2], vfB[3]);
        }
    }

    // publish l partials and the 3 non-own O quadrants
    Ls[w][0][l] = ls0;
    Ls[w][1][l] = ls1;
    #pragma unroll
    for (int c = 0; c < 4; ++c) {
        if (c == w) continue;                      // wave-uniform
        const int idx = (w < c) ? w : w - 1;
        const f32x16 src = (c == 0) ? o00 : (c == 1) ? o01 : (c == 2) ? o10 : o11;
        #pragma unroll
        for (int r = 0; r < 16; ++r)
            Cb[c][idx][r][l] = src[r];
    }
    __syncthreads();

    // each wave combines its own quadrant (qt = w>>1, et = w&1)
    f32x16 oc = (w == 0) ? o00 : (w == 1) ? o01 : (w == 2) ? o10 : o11;
    #pragma unroll
    for (int idx = 0; idx < 3; ++idx)
        #pragma unroll
        for (int r = 0; r < 16; ++r)
            oc[r] += Cb[w][idx][r][l];
    const int mqt = w >> 1, met = w & 1;
    float lt = 0.f;
    #pragma unroll
    for (int w2 = 0; w2 < 4; ++w2)
        lt += Ls[w2][mqt][lo] + Ls[w2][mqt][lo + 32];
    const float inv = 1.0f / lt;
    __syncthreads();

    // write bf16 pairs (packed u32) into stride-33 LDS tile (overlay on Cb)
    unsigned* l2 = (unsigned*)&Cb[0][0][0][0];
    #pragma unroll
    for (int rq = 0; rq < 4; ++rq) {
        #pragma unroll
        for (int ph = 0; ph < 2; ++ph) {
            const int r = 4 * rq + 2 * ph;
            const int col = met * 16 + 2 * hi + 4 * rq + ph;   // u32 col = e/2
            l2[(mqt * 32 + lo) * 33 + col] = pkbf(oc[r] * inv, oc[r + 1] * inv);
        }
    }
    __syncthreads();

    // cooperative coalesced ctx store: 64 rows x 64 bf16 (8 u32 per thread)
    {
        const int row = t >> 2, ch = (t & 3) * 8;
        short* crow = &ctx[((size_t)b * SEQ + qbase + row) * DM + h * DH];
        #pragma unroll
        for (int q = 0; q < 2; ++q) {
            uint4 u;
            u.x = l2[row * 33 + ch + q * 4 + 0];
            u.y = l2[row * 33 + ch + q * 4 + 1];
            u.z = l2[row * 33 + ch + q * 4 + 2];
            u.w = l2[row * 33 + ch + q * 4 + 3];
            *(uint4*)&crow[(ch + q * 4) * 2] = u;
        }
    }
}

// ---------------------------------------------------------------------------
// out_mfma: ctx(bf16) @ Wot(bf16) + bo -> out fp32.  128x64 tile, BK=64,
// single MFMA per product. grid (32, 12).
// ---------------------------------------------------------------------------
__global__ __launch_bounds__(256) void out_mfma(
    const short* __restrict__ ctx,
    const short* __restrict__ Wot,
    const float* __restrict__ bo, float* __restrict__ out)
{
    const int mt = blockIdx.x, ntl = blockIdx.y;
    __shared__ __align__(16) short Al[128 * 72];
    __shared__ __align__(16) short Bh[64 * 72];
    const int t = threadIdx.x;
    const int w = t >> 6, lane = t & 63, l15 = lane & 15, g = lane >> 4;
    const int m0 = mt * 128, n0 = ntl * 64;

    f32x4 acc[2][4];
    #pragma unroll
    for (int i = 0; i < 2; ++i)
        #pragma unroll
        for (int j = 0; j < 4; ++j) acc[i][j] = 0.f;

    for (int kt = 0; kt < DM / 64; ++kt) {
        const int k0 = kt * 64;
        {
            const int row = t >> 1, kc = (t & 1) * 32;
            #pragma unroll
            for (int q = 0; q < 4; ++q)
                *(s8v*)&Al[row * 72 + kc + q * 8] = *(const s8v*)&ctx[(size_t)(m0 + row) * DM + k0 + kc + q * 8];
        }
        {
            const int n = t >> 2, kc = (t & 3) * 16;
            *(s8v*)&Bh[n * 72 + kc]     = *(const s8v*)&Wot[(size_t)(n0 + n) * DM + k0 + kc];
            *(s8v*)&Bh[n * 72 + kc + 8] = *(const s8v*)&Wot[(size_t)(n0 + n) * DM + k0 + kc + 8];
        }
        __syncthreads();
        #pragma unroll
        for (int kk = 0; kk < 2; ++kk) {
            bfrag ah[2];
            #pragma unroll
            for (int i = 0; i < 2; ++i)
                ah[i] = *(const bfrag*)&Al[(w * 32 + 16 * i + l15) * 72 + kk * 32 + 8 * g];
            #pragma unroll
            for (int j = 0; j < 4; ++j) {
                const bfrag bh_ = *(const bfrag*)&Bh[(16 * j + l15) * 72 + kk * 32 + 8 * g];
                #pragma unroll
                for (int i = 0; i < 2; ++i)
                    acc[i][j] = MFMA(ah[i], bh_, acc[i][j]);
            }
        }
        __syncthreads();
    }

    #pragma unroll
    for (int j = 0; j < 4; ++j) {
        const int n = n0 + 16 * j + l15;
        const float bia = bo[n];
        #pragma unroll
        for (int i = 0; i < 2; ++i)
            #pragma unroll
            for (int r = 0; r < 4; ++r) {
                const int m = m0 + w * 32 + 16 * i + 4 * g + r;
                out[(size_t)m * DM + n] = acc[i][j][r] + bia;
            }
    }
}

// ---------------------------------------------------------------------------
extern "C" void kernel_launch(void* const* d_in, const int* in_sizes, int n_in,
                              void* d_out, int out_size, void* d_ws, size_t ws_size,
                              hipStream_t stream) {
    const float* x  = (const float*)d_in[0];
    const float* Wq = (const float*)d_in[1];
    const float* Wk = (const float*)d_in[2];
    const float* Wv = (const float*)d_in[3];
    const float* bq = (const float*)d_in[4];
    const float* bk = (const float*)d_in[5];
    const float* bv = (const float*)d_in[6];
    const float* Wo = (const float*)d_in[7];
    const float* bo = (const float*)d_in[8];
    float* out = (float*)d_out;

    char* ws = (char*)d_ws;
    short* xbf   = (short*)(ws);
    short* Wt    = (short*)(ws + 6291456);
    short* Wot   = (short*)(ws + 9830400);
    short* qb    = (short*)(ws + 12189696);
    short* kb    = (short*)(ws + 18481152);
    short* vtb   = (short*)(ws + 31064064);
    short* ctx   = (short*)(ws + 37355520);

    prep_all<<<2112, 256, 0, stream>>>(x, Wq, Wk, Wv, Wo, xbf, Wt, Wot);
    qkv_mfma<<<dim3(32, 18), 256, 0, stream>>>(xbf, Wt, bq, bk, bv, qb, kb, vtb);
    attn_mfma<<<768, 256, 0, stream>>>(qb, kb, vtb, ctx);
    out_mfma<<<dim3(32, 12), 256, 0, stream>>>(ctx, Wot, bo, out);
}

// Round 22
// 102.114 us; speedup vs baseline: 1.0131x; 1.0131x over previous
//
#include <hip/hip_runtime.h>
#include <hip/hip_bf16.h>
#include <math.h>

#define NH   12
#define DM   768
#define DH   64
#define NB   2
#define SEQ  2048

typedef short s8v  __attribute__((ext_vector_type(8)));
typedef short s4v  __attribute__((ext_vector_type(4)));
typedef float f32x4 __attribute__((ext_vector_type(4)));
typedef float f32x16 __attribute__((ext_vector_type(16)));
typedef s8v bfrag;

#define MFMA(a,b,c)   __builtin_amdgcn_mfma_f32_16x16x32_bf16(a,b,c,0,0,0)
#define MFMA32(a,b,c) __builtin_amdgcn_mfma_f32_32x32x16_bf16(a,b,c,0,0,0)

// 0.125 * log2(e)  (1/sqrt(DH) folded with base-2 exp)
#define QSCALE 0.18033688011112042f

__device__ __forceinline__ short f2bf(float f) {
    __hip_bfloat16 h = __float2bfloat16(f);
    return *(short*)&h;
}
__device__ __forceinline__ float bf2f(short s) {
    __hip_bfloat16 h; *(short*)&h = s;
    return __bfloat162float(h);
}
__device__ __forceinline__ float fexp2(float x) { return __builtin_amdgcn_exp2f(x); }
__device__ __forceinline__ unsigned pkbf(float a, float b) {
    unsigned r;
    asm("v_cvt_pk_bf16_f32 %0, %1, %2" : "=v"(r) : "v"(a), "v"(b));
    return r;
}
__device__ __forceinline__ void pl32swap(unsigned &a, unsigned &b) {
    asm volatile("v_permlane32_swap_b32 %0, %1" : "+v"(a), "+v"(b));
}
__device__ __forceinline__ bfrag mkfrag(unsigned d0, unsigned d1, unsigned d2, unsigned d3) {
    union { unsigned u[4]; bfrag f; } X;
    X.u[0] = d0; X.u[1] = d1; X.u[2] = d2; X.u[3] = d3;
    return X.f;
}

// ---------------------------------------------------------------------------
// prep_all: merged prep_x / prep_w / prep_wo (block-range dispatch).
// ---------------------------------------------------------------------------
__global__ __launch_bounds__(256) void prep_all(
    const float* __restrict__ x,
    const float* __restrict__ Wq, const float* __restrict__ Wk,
    const float* __restrict__ Wv, const float* __restrict__ Wo,
    short* __restrict__ xbf, short* __restrict__ Wt,
    short* __restrict__ Wot)
{
    const int bid = blockIdx.x;
    const int t = threadIdx.x;
    __shared__ __align__(16) short T0[64 * 72];

    if (bid < 1536) {
        const size_t gid = (size_t)bid * 256 + t;
        const float4 a = ((const float4*)x)[gid * 2];
        const float4 b = ((const float4*)x)[gid * 2 + 1];
        s8v o;
        o[0]=f2bf(a.x); o[1]=f2bf(a.y); o[2]=f2bf(a.z); o[3]=f2bf(a.w);
        o[4]=f2bf(b.x); o[5]=f2bf(b.y); o[6]=f2bf(b.z); o[7]=f2bf(b.w);
        *(s8v*)&xbf[gid * 8] = o;
    } else if (bid < 1968) {
        const int id = bid - 1536;
        const int dt = id % 12, mh = id / 12;
        const int mat = mh / NH, h = mh % NH;
        const float* W = (mat == 0 ? Wq : mat == 1 ? Wk : Wv) + (size_t)h * DM * DH;
        {
            const int r = t >> 2, e0 = (t & 3) * 16;
            #pragma unroll
            for (int q = 0; q < 4; ++q) {
                const float4 a = *(const float4*)&W[(size_t)(dt * 64 + r) * DH + e0 + q * 4];
                s4v s; s[0]=f2bf(a.x); s[1]=f2bf(a.y); s[2]=f2bf(a.z); s[3]=f2bf(a.w);
                *(s4v*)&T0[r * 72 + e0 + q * 4] = s;
            }
        }
        __syncthreads();
        {
            const int e = t >> 2, r0 = (t & 3) * 16;
            s8v s0, s1;
            #pragma unroll
            for (int i = 0; i < 8; ++i) { s0[i] = T0[(r0 + i) * 72 + e]; s1[i] = T0[(r0 + 8 + i) * 72 + e]; }
            short* dst = Wt + (size_t)mh * DH * DM + (size_t)e * DM + dt * 64 + r0;
            *(s8v*)&dst[0] = s0; *(s8v*)&dst[8] = s1;
        }
    } else {
        const int id = bid - 1968;
        const int ntl = id % 12, ktl = id / 12;
        {
            const int r = t >> 2, n0q = (t & 3) * 16;
            #pragma unroll
            for (int q = 0; q < 4; ++q) {
                const float4 a = *(const float4*)&Wo[(size_t)(ktl * 64 + r) * DM + ntl * 64 + n0q + q * 4];
                s4v s; s[0]=f2bf(a.x); s[1]=f2bf(a.y); s[2]=f2bf(a.z); s[3]=f2bf(a.w);
                *(s4v*)&T0[r * 72 + n0q + q * 4] = s;
            }
        }
        __syncthreads();
        {
            const int n = t >> 2, r0 = (t & 3) * 16;
            s8v h0, h1;
            #pragma unroll
            for (int i = 0; i < 8; ++i) {
                h0[i] = T0[(r0 + i) * 72 + n];
                h1[i] = T0[(r0 + 8 + i) * 72 + n];
            }
            const size_t off = (size_t)(ntl * 64 + n) * DM + ktl * 64 + r0;
            *(s8v*)&Wot[off] = h0; *(s8v*)&Wot[off + 8] = h1;
        }
    }
}

// ---------------------------------------------------------------------------
// qkv_mfma: 128m x 128n tile (TWO heads per block), BK=64, reg-staged.
// grid (32,18). Q written [bh][s][e] pre-scaled by QSCALE.
// K written FRAGMENT-LINEAR:  K_swz[bh][s/32][e/16][(e%16)/8][s%32][e%8]
// V written FRAGMENT-LINEAR:  V_swz[bh][k/32][e/32][(k%32)/16][(k%16)/8][e%32][k%8]
// so attn's per-lane fragment loads are 1KB-contiguous (coalesced).
// ---------------------------------------------------------------------------
__global__ __launch_bounds__(256) void qkv_mfma(
    const short* __restrict__ xbf, const short* __restrict__ Wt,
    const float* __restrict__ bq, const float* __restrict__ bk,
    const float* __restrict__ bv,
    short* __restrict__ qo, short* __restrict__ ko, short* __restrict__ vto)
{
    const int mt = blockIdx.x, sp = blockIdx.y;
    const int slab0 = sp * 2;
    const int mat = slab0 / NH, h0 = slab0 % NH;
    __shared__ __align__(16) short Al[128 * 72];
    __shared__ __align__(16) short Bl[128 * 72];
    const int t = threadIdx.x;
    const int w = t >> 6, lane = t & 63, l15 = lane & 15, g = lane >> 4;
    const int m0 = mt * 128;
    const short* Ws = Wt + (size_t)slab0 * DH * DM;   // 2 slabs contiguous

    f32x4 acc[2][8];
    #pragma unroll
    for (int i = 0; i < 2; ++i)
        #pragma unroll
        for (int j = 0; j < 8; ++j) acc[i][j] = 0.f;

    for (int kt = 0; kt < DM / 64; ++kt) {
        const int k0 = kt * 64;
        {
            const int row = t >> 1, kc = (t & 1) * 32;
            #pragma unroll
            for (int q = 0; q < 4; ++q)
                *(s8v*)&Al[row * 72 + kc + q * 8] = *(const s8v*)&xbf[(size_t)(m0 + row) * DM + k0 + kc + q * 8];
            #pragma unroll
            for (int q = 0; q < 4; ++q)
                *(s8v*)&Bl[row * 72 + kc + q * 8] = *(const s8v*)&Ws[(size_t)row * DM + k0 + kc + q * 8];
        }
        __syncthreads();
        #pragma unroll
        for (int kk = 0; kk < 2; ++kk) {
            bfrag a[2], b[8];
            #pragma unroll
            for (int i = 0; i < 2; ++i) a[i] = *(const bfrag*)&Al[(w * 32 + 16 * i + l15) * 72 + kk * 32 + 8 * g];
            #pragma unroll
            for (int j = 0; j < 8; ++j) b[j] = *(const bfrag*)&Bl[(16 * j + l15) * 72 + kk * 32 + 8 * g];
            #pragma unroll
            for (int i = 0; i < 2; ++i)
                #pragma unroll
                for (int j = 0; j < 8; ++j) acc[i][j] = MFMA(a[i], b[j], acc[i][j]);
        }
        __syncthreads();
    }

    const float* bias0 = (mat == 0 ? bq : mat == 1 ? bk : bv);
    if (mat == 0) {
        #pragma unroll
        for (int j = 0; j < 8; ++j) {
            const int h = h0 + (j >> 2);
            const int n = (j & 3) * 16 + l15;
            const float bia = bias0[h * DH + n];
            #pragma unroll
            for (int i = 0; i < 2; ++i)
                #pragma unroll
                for (int r = 0; r < 4; ++r) {
                    const int m = m0 + w * 32 + 16 * i + 4 * g + r;
                    const int bb = m >> 11, s = m & (SEQ - 1);
                    qo[(((size_t)bb * NH + h) * SEQ + s) * DH + n] = f2bf((acc[i][j][r] + bia) * QSCALE);
                }
        }
    } else if (mat == 1) {
        // K fragment-linear: idx = (s>>5)*2048 + (j&3)*512 + (l15>>3)*256 + (s&31)*8 + (l15&7)
        #pragma unroll
        for (int j = 0; j < 8; ++j) {
            const int h = h0 + (j >> 2);
            const int n = (j & 3) * 16 + l15;
            const float bia = bias0[h * DH + n];
            #pragma unroll
            for (int i = 0; i < 2; ++i)
                #pragma unroll
                for (int r = 0; r < 4; ++r) {
                    const int m = m0 + w * 32 + 16 * i + 4 * g + r;
                    const int bb = m >> 11, s = m & (SEQ - 1);
                    ko[((size_t)bb * NH + h) * (SEQ * DH) + (size_t)(s >> 5) * 2048
                       + (j & 3) * 512 + (l15 >> 3) * 256 + (s & 31) * 8 + (l15 & 7)]
                        = f2bf(acc[i][j][r] + bia);
                }
        }
    } else {
        // V fragment-linear: idx = (k>>5)*2048 + ((j&3)>>1)*1024 + i*512
        //                        + (g>>1)*256 + ((j&1)*16 + l15)*8 + (g&1)*4
        #pragma unroll
        for (int j = 0; j < 8; ++j) {
            const int h = h0 + (j >> 2);
            const int n = (j & 3) * 16 + l15;
            const float bia = bias0[h * DH + n];
            #pragma unroll
            for (int i = 0; i < 2; ++i) {
                const int m = m0 + w * 32 + 16 * i + 4 * g;
                const int bb = m >> 11, k = m & (SEQ - 1);
                s4v sv;
                #pragma unroll
                for (int r = 0; r < 4; ++r) sv[r] = f2bf(acc[i][j][r] + bia);
                *(s4v*)&vto[((size_t)bb * NH + h) * (SEQ * DH) + (size_t)(k >> 5) * 2048
                            + ((j & 3) >> 1) * 1024 + i * 512
                            + (g >> 1) * 256 + ((j & 1) * 16 + l15) * 8 + (g & 1) * 4] = sv;
            }
        }
    }
}

// ---------------------------------------------------------------------------
// attn_mfma: r11 main loop + setprio; K/V in fragment-linear layouts so
// every kf/vf load is a fully-coalesced contiguous 1KB wave load (8 cache
// lines vs 32 strided). Flat grid 768, XCD-swizzled. 4 waves; each wave:
// 64 q-rows x one KV quarter. 48KB combine; ctx written as bf16 [B,S,D].
// ---------------------------------------------------------------------------
__global__ __launch_bounds__(256, 4) void attn_mfma(
    const short* __restrict__ qg, const short* __restrict__ kg,
    const short* __restrict__ vtg, short* __restrict__ ctx)
{
    // n = 8*(qb*3 + bh%3) + bh/3  <=>  xcd=n&7, s=n>>3, bh=xcd*3+s%3, qb=s/3
    const int n_  = blockIdx.x;
    const int xcd = n_ & 7, s_ = n_ >> 3;
    const int bh = xcd * 3 + (s_ % 3);
    const int qb = s_ / 3;
    const int b = bh / NH, h = bh % NH;

    __shared__ __align__(16) float Cb[4][3][16][64];  // 48KB: combine buffer
    __shared__ float Ls[4][2][64];                     // 2KB: l partials

    const int t = threadIdx.x;
    const int w = t >> 6, l = t & 63, lo = l & 31, hi = l >> 5;
    const size_t base  = (size_t)bh * SEQ * DH;
    const int qbase = qb * 64;

    // Q fragments (B operand), Q pre-scaled by QSCALE
    bfrag qf[2][4];
    #pragma unroll
    for (int qt = 0; qt < 2; ++qt)
        #pragma unroll
        for (int esl = 0; esl < 4; ++esl)
            qf[qt][esl] = *(const bfrag*)&qg[base + (size_t)(qbase + qt * 32 + lo) * DH + esl * 16 + hi * 8];

    f32x16 o00, o01, o10, o11;   // o[q-tile][e-tile]
    o00 = 0.f; o01 = 0.f; o10 = 0.f; o11 = 0.f;
    float ls0 = 0.f, ls1 = 0.f;

    const short* kbp = kg + base;    // fragment-linear K
    const short* vbp = vtg + base;   // fragment-linear V
    const int kb0 = w * 16;          // this wave's first 32-row KV chunk

    // softmax + PV step (captures accumulators by reference)
    auto SMPV = [&](const f32x16& s0, const f32x16& s1,
                    const bfrag& vf00, const bfrag& vf01,
                    const bfrag& vf10, const bfrag& vf11) {
        float p0[16], p1[16];
        #pragma unroll
        for (int i = 0; i < 16; ++i) p0[i] = fexp2(s0[i]);
        #pragma unroll
        for (int i = 0; i < 16; ++i) p1[i] = fexp2(s1[i]);
        ls0 += ((p0[0]+p0[1])+(p0[2]+p0[3])) + ((p0[4]+p0[5])+(p0[6]+p0[7]))
             + ((p0[8]+p0[9])+(p0[10]+p0[11])) + ((p0[12]+p0[13])+(p0[14]+p0[15]));
        ls1 += ((p1[0]+p1[1])+(p1[2]+p1[3])) + ((p1[4]+p1[5])+(p1[6]+p1[7]))
             + ((p1[8]+p1[9])+(p1[10]+p1[11])) + ((p1[12]+p1[13])+(p1[14]+p1[15]));

        unsigned a0 = pkbf(p0[0],  p0[1]),  a1 = pkbf(p0[2],  p0[3]);
        unsigned a2 = pkbf(p0[4],  p0[5]),  a3 = pkbf(p0[6],  p0[7]);
        unsigned c0_ = pkbf(p0[8], p0[9]),  c1_ = pkbf(p0[10], p0[11]);
        unsigned c2_ = pkbf(p0[12], p0[13]), c3_ = pkbf(p0[14], p0[15]);
        pl32swap(a0, a2); pl32swap(a1, a3); pl32swap(c0_, c2_); pl32swap(c1_, c3_);
        const bfrag pa00 = mkfrag(a0, a1, a2, a3);
        const bfrag pa01 = mkfrag(c0_, c1_, c2_, c3_);

        unsigned d0 = pkbf(p1[0],  p1[1]),  d1 = pkbf(p1[2],  p1[3]);
        unsigned d2 = pkbf(p1[4],  p1[5]),  d3 = pkbf(p1[6],  p1[7]);
        unsigned e0_ = pkbf(p1[8], p1[9]),  e1_ = pkbf(p1[10], p1[11]);
        unsigned e2_ = pkbf(p1[12], p1[13]), e3_ = pkbf(p1[14], p1[15]);
        pl32swap(d0, d2); pl32swap(d1, d3); pl32swap(e0_, e2_); pl32swap(e1_, e3_);
        const bfrag pa10 = mkfrag(d0, d1, d2, d3);
        const bfrag pa11 = mkfrag(e0_, e1_, e2_, e3_);

        __builtin_amdgcn_s_setprio(1);
        o00 = MFMA32(vf00, pa00, o00); o00 = MFMA32(vf01, pa01, o00);
        o10 = MFMA32(vf00, pa10, o10); o10 = MFMA32(vf01, pa11, o10);
        o01 = MFMA32(vf10, pa00, o01); o01 = MFMA32(vf11, pa01, o01);
        o11 = MFMA32(vf10, pa10, o11); o11 = MFMA32(vf11, pa11, o11);
        __builtin_amdgcn_s_setprio(0);
    };

    bfrag kfA[4], kfB[4];
    bfrag vfA[4], vfB[4];
    // prologue: K and V for iteration 0 (contiguous 1KB loads)
    #pragma unroll
    for (int esl = 0; esl < 4; ++esl)
        kfA[esl] = *(const bfrag*)&kbp[(size_t)kb0 * 2048 + esl * 512 + l * 8];
    #pragma unroll
    for (int q = 0; q < 4; ++q)
        vfA[q] = *(const bfrag*)&vbp[(size_t)kb0 * 2048 + q * 512 + l * 8];

    for (int it2 = 0; it2 < 8; ++it2) {
        // ---- even iteration: current in A, prefetch into B ----
        {
            const int it = 2 * it2;
            f32x16 s0, s1; s0 = 0.f; s1 = 0.f;
            __builtin_amdgcn_s_setprio(1);
            #pragma unroll
            for (int esl = 0; esl < 4; ++esl) {
                s0 = MFMA32(kfA[esl], qf[0][esl], s0);
                s1 = MFMA32(kfA[esl], qf[1][esl], s1);
            }
            __builtin_amdgcn_s_setprio(0);
            // prefetch K,V for iter+1 (covered by softmax+PV below)
            {
                const size_t co = (size_t)(kb0 + it + 1) * 2048;
                #pragma unroll
                for (int esl = 0; esl < 4; ++esl)
                    kfB[esl] = *(const bfrag*)&kbp[co + esl * 512 + l * 8];
                #pragma unroll
                for (int q = 0; q < 4; ++q)
                    vfB[q] = *(const bfrag*)&vbp[co + q * 512 + l * 8];
            }
            SMPV(s0, s1, vfA[0], vfA[1], vfA[2], vfA[3]);
        }
        // ---- odd iteration: current in B, prefetch into A ----
        {
            const int it = 2 * it2 + 1;
            f32x16 s0, s1; s0 = 0.f; s1 = 0.f;
            __builtin_amdgcn_s_setprio(1);
            #pragma unroll
            for (int esl = 0; esl < 4; ++esl) {
                s0 = MFMA32(kfB[esl], qf[0][esl], s0);
                s1 = MFMA32(kfB[esl], qf[1][esl], s1);
            }
            __builtin_amdgcn_s_setprio(0);
            if (it2 < 7) {
                const size_t co = (size_t)(kb0 + it + 1) * 2048;
                #pragma unroll
                for (int esl = 0; esl < 4; ++esl)
                    kfA[esl] = *(const bfrag*)&kbp[co + esl * 512 + l * 8];
                #pragma unroll
                for (int q = 0; q < 4; ++q)
                    vfA[q] = *(const bfrag*)&vbp[co + q * 512 + l * 8];
            }
            SMPV(s0, s1, vfB[0], vfB[1], vfB[2], vfB[3]);
        }
    }

    // publish l partials and the 3 non-own O quadrants
    Ls[w][0][l] = ls0;
    Ls[w][1][l] = ls1;
    #pragma unroll
    for (int c = 0; c < 4; ++c) {
        if (c == w) continue;                      // wave-uniform
        const int idx = (w < c) ? w : w - 1;
        const f32x16 src = (c == 0) ? o00 : (c == 1) ? o01 : (c == 2) ? o10 : o11;
        #pragma unroll
        for (int r = 0; r < 16; ++r)
            Cb[c][idx][r][l] = src[r];
    }
    __syncthreads();

    // each wave combines its own quadrant (qt = w>>1, et = w&1)
    f32x16 oc = (w == 0) ? o00 : (w == 1) ? o01 : (w == 2) ? o10 : o11;
    #pragma unroll
    for (int idx = 0; idx < 3; ++idx)
        #pragma unroll
        for (int r = 0; r < 16; ++r)
            oc[r] += Cb[w][idx][r][l];
    const int mqt = w >> 1, met = w & 1;
    float lt = 0.f;
    #pragma unroll
    for (int w2 = 0; w2 < 4; ++w2)
        lt += Ls[w2][mqt][lo] + Ls[w2][mqt][lo + 32];
    const float inv = 1.0f / lt;
    __syncthreads();

    // write bf16 pairs (packed u32) into stride-33 LDS tile (overlay on Cb)
    unsigned* l2 = (unsigned*)&Cb[0][0][0][0];
    #pragma unroll
    for (int rq = 0; rq < 4; ++rq) {
        #pragma unroll
        for (int ph = 0; ph < 2; ++ph) {
            const int r = 4 * rq + 2 * ph;
            const int col = met * 16 + 2 * hi + 4 * rq + ph;   // u32 col = e/2
            l2[(mqt * 32 + lo) * 33 + col] = pkbf(oc[r] * inv, oc[r + 1] * inv);
        }
    }
    __syncthreads();

    // cooperative coalesced ctx store: 64 rows x 64 bf16 (8 u32 per thread)
    {
        const int row = t >> 2, ch = (t & 3) * 8;
        short* crow = &ctx[((size_t)b * SEQ + qbase + row) * DM + h * DH];
        #pragma unroll
        for (int q = 0; q < 2; ++q) {
            uint4 u;
            u.x = l2[row * 33 + ch + q * 4 + 0];
            u.y = l2[row * 33 + ch + q * 4 + 1];
            u.z = l2[row * 33 + ch + q * 4 + 2];
            u.w = l2[row * 33 + ch + q * 4 + 3];
            *(uint4*)&crow[(ch + q * 4) * 2] = u;
        }
    }
}

// ---------------------------------------------------------------------------
// out_mfma: ctx(bf16) @ Wot(bf16) + bo -> out fp32.  128x64 tile, BK=64,
// single MFMA per product. grid (32, 12).
// ---------------------------------------------------------------------------
__global__ __launch_bounds__(256) void out_mfma(
    const short* __restrict__ ctx,
    const short* __restrict__ Wot,
    const float* __restrict__ bo, float* __restrict__ out)
{
    const int mt = blockIdx.x, ntl = blockIdx.y;
    __shared__ __align__(16) short Al[128 * 72];
    __shared__ __align__(16) short Bh[64 * 72];
    const int t = threadIdx.x;
    const int w = t >> 6, lane = t & 63, l15 = lane & 15, g = lane >> 4;
    const int m0 = mt * 128, n0 = ntl * 64;

    f32x4 acc[2][4];
    #pragma unroll
    for (int i = 0; i < 2; ++i)
        #pragma unroll
        for (int j = 0; j < 4; ++j) acc[i][j] = 0.f;

    for (int kt = 0; kt < DM / 64; ++kt) {
        const int k0 = kt * 64;
        {
            const int row = t >> 1, kc = (t & 1) * 32;
            #pragma unroll
            for (int q = 0; q < 4; ++q)
                *(s8v*)&Al[row * 72 + kc + q * 8] = *(const s8v*)&ctx[(size_t)(m0 + row) * DM + k0 + kc + q * 8];
        }
        {
            const int n = t >> 2, kc = (t & 3) * 16;
            *(s8v*)&Bh[n * 72 + kc]     = *(const s8v*)&Wot[(size_t)(n0 + n) * DM + k0 + kc];
            *(s8v*)&Bh[n * 72 + kc + 8] = *(const s8v*)&Wot[(size_t)(n0 + n) * DM + k0 + kc + 8];
        }
        __syncthreads();
        #pragma unroll
        for (int kk = 0; kk < 2; ++kk) {
            bfrag ah[2];
            #pragma unroll
            for (int i = 0; i < 2; ++i)
                ah[i] = *(const bfrag*)&Al[(w * 32 + 16 * i + l15) * 72 + kk * 32 + 8 * g];
            #pragma unroll
            for (int j = 0; j < 4; ++j) {
                const bfrag bh_ = *(const bfrag*)&Bh[(16 * j + l15) * 72 + kk * 32 + 8 * g];
                #pragma unroll
                for (int i = 0; i < 2; ++i)
                    acc[i][j] = MFMA(ah[i], bh_, acc[i][j]);
            }
        }
        __syncthreads();
    }

    #pragma unroll
    for (int j = 0; j < 4; ++j) {
        const int n = n0 + 16 * j + l15;
        const float bia = bo[n];
        #pragma unroll
        for (int i = 0; i < 2; ++i)
            #pragma unroll
            for (int r = 0; r < 4; ++r) {
                const int m = m0 + w * 32 + 16 * i + 4 * g + r;
                out[(size_t)m * DM + n] = acc[i][j][r] + bia;
            }
    }
}

// ---------------------------------------------------------------------------
extern "C" void kernel_launch(void* const* d_in, const int* in_sizes, int n_in,
                              void* d_out, int out_size, void* d_ws, size_t ws_size,
                              hipStream_t stream) {
    const float* x  = (const float*)d_in[0];
    const float* Wq = (const float*)d_in[1];
    const float* Wk = (const float*)d_in[2];
    const float* Wv = (const float*)d_in[3];
    const float* bq = (const float*)d_in[4];
    const float* bk = (const float*)d_in[5];
    const float* bv = (const float*)d_in[6];
    const float* Wo = (const float*)d_in[7];
    const float* bo = (const float*)d_in[8];
    float* out = (float*)d_out;

    char* ws = (char*)d_ws;
    short* xbf   = (short*)(ws);
    short* Wt    = (short*)(ws + 6291456);
    short* Wot   = (short*)(ws + 9830400);
    short* qb    = (short*)(ws + 12189696);
    short* kb    = (short*)(ws + 18481152);
    short* vtb   = (short*)(ws + 31064064);
    short* ctx   = (short*)(ws + 37355520);

    prep_all<<<2112, 256, 0, stream>>>(x, Wq, Wk, Wv, Wo, xbf, Wt, Wot);
    qkv_mfma<<<dim3(32, 18), 256, 0, stream>>>(xbf, Wt, bq, bk, bv, qb, kb, vtb);
    attn_mfma<<<768, 256, 0, stream>>>(qb, kb, vtb, ctx);
    out_mfma<<<dim3(32, 12), 256, 0, stream>>>(ctx, Wot, bo, out);
}